// Round 4
// baseline (607.763 us; speedup 1.0000x reference)
//
#include <hip/hip_runtime.h>
#include <hip/hip_cooperative_groups.h>
#include <hip/hip_bf16.h>
#include <math.h>

namespace cg = cooperative_groups;

#define N_NODES 100000
#define C 256
#define NB 64
#define H1D 128
#define NG 128
#define BN_EPS 1e-5f

#define BLKN 32                           // rows per subtile
#define NSUB (N_NODES / BLKN)             // 3125 subtiles, exact
#define COOP_MAX 1024                     // preferred cooperative grid (4 blk/CU)

// fallback (round-2, known-good) geometry
#define FB_ROWS 64
#define FB_SUBT 2
#define FB_NBLK ((N_NODES + FB_ROWS - 1) / FB_ROWS)   // 1563
#define PBN_ROWS FB_NBLK                  // pbn sized for the larger user

// per-graph record: XC[256] | XS[256] | BS[256] (b*4+{CV,SV,CC,CS}) | cnt
#define GREC 769

// ws layout (float offsets)
#define OFF_GSUMS 0
#define OFF_BNSUM (NG * GREC)            // 98432
#define OFF_BNSQ  (OFF_BNSUM + 256)      // 98688
#define ZERO_FLOATS (OFF_BNSQ + 256)     // 98944 floats zeroed before P1 atomics
#define OFF_HMEAN ZERO_FLOATS            // 98944
#define OFF_WT1   (OFF_HMEAN + NG * C)   // +32768
#define OFF_WT2   (OFF_WT1 + 16896)
#define OFF_CSN   (OFF_WT2 + 4352)       // N*128 bf16 = 6.4M floats
#define OFF_PBN   (OFF_CSN + N_NODES * 64)   // PBN_ROWS x 512 fp32 BN partials

#define WT1_LD 264   // bf16 stride of Wt1 in global (16B-aligned rows)
#define WT2_LD 136
#define XS_LD  272   // bf16 LDS stride: row shift = 8 banks -> 4-way max on b128

typedef __attribute__((ext_vector_type(8))) short bf16x8;
typedef __attribute__((ext_vector_type(4))) float f32x4;

struct __align__(8) bf4 { __hip_bfloat16 x, y, z, w; };

__device__ __forceinline__ float bf2f(__hip_bfloat16 h) { return __bfloat162float(h); }

__device__ __forceinline__ float fast_tanh(float y) {
    float e = __expf(2.f * y);
    return 1.f - 2.f / (e + 1.f);
}
__device__ __forceinline__ float fast_gelu(float v) {
    float u = 0.7978845608f * (v + 0.044715f * v * v * v);
    return 0.5f * v * (1.f + fast_tanh(u));
}

// ===========================================================================
// Cooperative fused kernel: 4 phases separated by grid.sync().
// Work split derived from gridDim.x at runtime (host picks a grid the
// runtime's occupancy calculator guarantees is fully co-resident).
// ===========================================================================
__global__ __launch_bounds__(256, 4)
void fused(const float* __restrict__ x,
           const int* __restrict__ batch,
           const float* __restrict__ W1, const float* __restrict__ b1,
           const float* __restrict__ W2, const float* __restrict__ b2,
           const float* __restrict__ lin_w, const float* __restrict__ lin_b,
           const float* __restrict__ gamma, const float* __restrict__ beta,
           float* __restrict__ ws, float* __restrict__ out)
{
    __shared__ __hip_bfloat16 xs[BLKN][XS_LD];  // 17408 B
    __shared__ char sm_u[BLKN * WT2_LD * 2];    // 8704 B: h1s / csn / P3 coeffs
    __shared__ int gsh[BLKN];                   // 128 B  -> 26240 B total
    auto h1s = (__hip_bfloat16 (*)[WT2_LD])sm_u;   // stride 136
    auto csn = (__hip_bfloat16 (*)[132])sm_u;      // stride 132: [2c]=cos,[2c+1]=sin

    float* gsums = ws + OFF_GSUMS;
    float* bnsum = ws + OFF_BNSUM;
    float* bnsq  = ws + OFF_BNSQ;
    float* hmean = ws + OFF_HMEAN;
    __hip_bfloat16* Wt1g = (__hip_bfloat16*)(ws + OFF_WT1);
    __hip_bfloat16* Wt2g = (__hip_bfloat16*)(ws + OFF_WT2);
    __hip_bfloat16* csng = (__hip_bfloat16*)(ws + OFF_CSN);
    float* pbn   = ws + OFF_PBN;

    cg::grid_group gg = cg::this_grid();

    const int nblk = gridDim.x;           // multiple of 128, >= 512
    const int bid = blockIdx.x;
    const int t = threadIdx.x;
    const int w = t >> 6;
    const int l = t & 63;
    const int lo = l & 15, quad = l >> 4;

    // ================= Phase 0: zero stats + weight transpose =================
    {
        for (int i = bid * 256 + t; i < ZERO_FLOATS; i += nblk * 256)
            ws[i] = 0.f;
        if (bid < 32) {
            const int t0 = bid * 256 + t;
            for (int j = t0; j < 128 * 256; j += 8192) {
                int nn = j >> 8, k = j & 255;
                Wt1g[nn * WT1_LD + k] = __float2bfloat16(W1[k * 128 + nn]);
            }
            for (int j = t0; j < 64 * 128; j += 8192) {
                int nn = j >> 7, k = j & 127;
                Wt2g[nn * WT2_LD + k] = __float2bfloat16(W2[k * 64 + nn]);
            }
        }
    }
    __threadfence();
    gg.sync();

    // ================= Phase 1: angles + rotation + pooled stats ==============
    {
        const int base_cnt = NSUB / nblk;
        const int rem = NSUB - base_cnt * nblk;
        const int scnt = base_cnt + (bid < rem ? 1 : 0);
        const int sstart = base_cnt * bid + (bid < rem ? bid : rem);

        const short* w1base = (const short*)Wt1g + (w * 32 + lo) * WT1_LD + quad * 8;
        const int mw = w >> 1;
        const int nb0 = (w & 1) * 32;
        const short* w2base = (const short*)Wt2g + (nb0 + lo) * WT2_LD + quad * 8;
        const float bb1_0 = b1[w * 32 + lo];
        const float bb1_1 = b1[w * 32 + 16 + lo];
        const float bb2_0 = b2[nb0 + lo];
        const float bb2_1 = b2[nb0 + 16 + lo];

        const int pr = t >> 6;            // rows pr, pr+4, ..., pr+28
        const int pc4 = (t & 63) * 4;

        const int c = t;
        const int b = c >> 2;
        const int idx2 = c & 3;
        float xc_a = 0.f, xs_a = 0.f, st = 0.f, rcnt = 0.f;
        float xm = 0.f, xq = 0.f;
        int gprev = -1;

#define FLUSH_G(gidx) do {                               \
        float* rec = gsums + (size_t)(gidx) * GREC;      \
        atomicAdd(&rec[c], xc_a);                        \
        atomicAdd(&rec[256 + c], xs_a);                  \
        atomicAdd(&rec[512 + c], st);                    \
        if (c == 0) atomicAdd(&rec[768], rcnt);          \
    } while (0)

        // prologue: load first subtile into registers
        float4 pf[8];
        int pb = 0;
        {
            const int n0 = sstart * BLKN;
            #pragma unroll
            for (int m = 0; m < 8; ++m)
                pf[m] = *(const float4*)(x + (size_t)(n0 + pr + m * 4) * C + pc4);
            if (t < BLKN) pb = batch[n0 + t];
        }

        for (int sub = 0; sub < scnt; ++sub) {
            const int n0 = (sstart + sub) * BLKN;

            // Phase A: registers -> bf16 LDS tile; batch tile
            #pragma unroll
            for (int m = 0; m < 8; ++m) {
                bf4 pk;
                pk.x = __float2bfloat16(pf[m].x); pk.y = __float2bfloat16(pf[m].y);
                pk.z = __float2bfloat16(pf[m].z); pk.w = __float2bfloat16(pf[m].w);
                *(bf4*)&xs[pr + m * 4][pc4] = pk;
            }
            if (t < BLKN) gsh[t] = pb;

            // prefetch next subtile (hides HBM latency under compute below)
            if (sub + 1 < scnt) {
                const int n1 = n0 + BLKN;
                #pragma unroll
                for (int m = 0; m < 8; ++m)
                    pf[m] = *(const float4*)(x + (size_t)(n1 + pr + m * 4) * C + pc4);
                if (t < BLKN) pb = batch[n1 + t];
            }
            __syncthreads();

            // GEMM1: h1 = x[32,256] @ W1[256,128]
            f32x4 acc1[2][2];
            #pragma unroll
            for (int mt = 0; mt < 2; ++mt) { acc1[mt][0] = (f32x4)0.f; acc1[mt][1] = (f32x4)0.f; }
            #pragma unroll
            for (int k = 0; k < 8; ++k) {
                bf16x8 bA = *(const bf16x8*)(w1base + k * 32);
                bf16x8 bB = *(const bf16x8*)(w1base + 16 * WT1_LD + k * 32);
                #pragma unroll
                for (int mt = 0; mt < 2; ++mt) {
                    bf16x8 afr = *(const bf16x8*)&xs[mt * 16 + lo][k * 32 + quad * 8];
                    acc1[mt][0] = __builtin_amdgcn_mfma_f32_16x16x32_bf16(afr, bA, acc1[mt][0], 0, 0, 0);
                    acc1[mt][1] = __builtin_amdgcn_mfma_f32_16x16x32_bf16(afr, bB, acc1[mt][1], 0, 0, 0);
                }
            }
            #pragma unroll
            for (int nt = 0; nt < 2; ++nt) {
                const float bb = nt ? bb1_1 : bb1_0;
                #pragma unroll
                for (int mt = 0; mt < 2; ++mt) {
                    #pragma unroll
                    for (int r = 0; r < 4; ++r) {
                        float v = fast_gelu(acc1[mt][nt][r] + bb);
                        h1s[mt * 16 + quad * 4 + r][w * 32 + nt * 16 + lo] = __float2bfloat16(v);
                    }
                }
            }
            __syncthreads();

            // GEMM2: ang = h1[32,128] @ W2[128,64]
            f32x4 acc2[2];
            acc2[0] = (f32x4)0.f; acc2[1] = (f32x4)0.f;
            #pragma unroll
            for (int k = 0; k < 4; ++k) {
                bf16x8 afr = *(const bf16x8*)&h1s[mw * 16 + lo][k * 32 + quad * 8];
                bf16x8 bA = *(const bf16x8*)(w2base + k * 32);
                bf16x8 bB = *(const bf16x8*)(w2base + 16 * WT2_LD + k * 32);
                acc2[0] = __builtin_amdgcn_mfma_f32_16x16x32_bf16(afr, bA, acc2[0], 0, 0, 0);
                acc2[1] = __builtin_amdgcn_mfma_f32_16x16x32_bf16(afr, bB, acc2[1], 0, 0, 0);
            }
            __syncthreads();   // h1s reads done; csn may overwrite same LDS

            #pragma unroll
            for (int nt = 0; nt < 2; ++nt) {
                const int col = nb0 + nt * 16 + lo;
                const float bb = nt ? bb2_1 : bb2_0;
                #pragma unroll
                for (int r = 0; r < 4; ++r) {
                    float a = fast_tanh(acc2[nt][r] + bb);
                    union { unsigned int u; __hip_bfloat16 h[2]; } p;
                    p.h[0] = __float2bfloat16(__cosf(a));
                    p.h[1] = __float2bfloat16(__sinf(a));
                    *(unsigned int*)&csn[mw * 16 + quad * 4 + r][2 * col] = p.u;
                }
            }
            __syncthreads();

            // coalesced global write of interleaved cos/sin
            #pragma unroll
            for (int m = 0; m < 4; ++m) {
                int idx = t + m * 256;
                int row = idx >> 5;
                int q = (idx & 31);
                uint2 v = *(const uint2*)&csn[row][q * 4];
                *(uint2*)(csng + (size_t)(n0 + row) * 128 + q * 4) = v;
            }

            // Phase D: per-graph stat accumulation (thread = channel)
            #pragma unroll 8
            for (int r = 0; r < BLKN; ++r) {
                const int g = gsh[r];
                if (g != gprev) {
                    if (gprev >= 0) FLUSH_G(gprev);
                    xc_a = 0.f; xs_a = 0.f; st = 0.f; rcnt = 0.f;
                    gprev = g;
                }
                const float xv = bf2f(xs[r][c]);
                union { unsigned int u; __hip_bfloat16 h[2]; } cs;
                cs.u = *(const unsigned int*)&csn[r][2 * b];
                const float cv = bf2f(cs.h[0]);
                const float sv = bf2f(cs.h[1]);
                xc_a += xv * cv;
                xs_a += xv * sv;
                xm += xv;
                xq += xv * xv;
                st += (idx2 == 0) ? cv : (idx2 == 1) ? sv : (idx2 == 2) ? cv * cv : cv * sv;
                rcnt += 1.f;
            }
            __syncthreads();
        }

        if (gprev >= 0) FLUSH_G(gprev);
#undef FLUSH_G
        pbn[(size_t)bid * 512 + t] = xm;
        pbn[(size_t)bid * 512 + 256 + t] = xq;
    }
    __threadfence();
    gg.sync();

    // ================= Phase 2: hmean + BN closed form (blocks 0..127) ========
    if (bid < NG) {
        float* xsh = (float*)&xs[0][0];          // alias: 1281 floats
        float* xc   = xsh;
        float* xsv  = xsh + 256;
        float* bs4  = xsh + 512;
        float* grot = xsh + 768;
        float* hm   = xsh + 1024;
        const int g = bid;

        // BN-partial reduction: coalesced chunk of pbn rows, all 512 channels
        {
            const int chunk = nblk >> 7;          // nblk multiple of 128
            const int r0 = g * chunk;
            float a0 = 0.f, a1 = 0.f;
            for (int r = r0; r < r0 + chunk; ++r) {
                a0 += pbn[(size_t)r * 512 + t];
                a1 += pbn[(size_t)r * 512 + 256 + t];
            }
            atomicAdd(&bnsum[t], a0);
            atomicAdd(&bnsq[t], a1);
        }

        const float* rec = gsums + (size_t)g * GREC;
        xc[t]  = rec[t];
        xsv[t] = rec[256 + t];
        bs4[t] = rec[512 + t];
        if (t == 0) xsh[1280] = rec[768];
        __syncthreads();

        const int b = t >> 2, idx2 = t & 3, i2 = idx2 >> 1;
        grot[t] = (i2 == 0) ? (xc[t] - xsv[t + 2]) : (xsv[t - 2] + xc[t]);
        __syncthreads();

        float a0 = 0.f, a1 = 0.f, a2 = 0.f, a3 = 0.f;
        #pragma unroll 4
        for (int k = 0; k < C; k += 4) {
            a0 += grot[k + 0] * lin_w[(size_t)(k + 0) * C + t];
            a1 += grot[k + 1] * lin_w[(size_t)(k + 1) * C + t];
            a2 += grot[k + 2] * lin_w[(size_t)(k + 2) * C + t];
            a3 += grot[k + 3] * lin_w[(size_t)(k + 3) * C + t];
        }
        const float cnt = xsh[1280];
        const float hv = (cnt > 0.f) ? ((a0 + a1 + a2 + a3) / cnt + lin_b[t]) : 0.f;
        hm[t] = hv;
        hmean[g * C + t] = hv;
        __syncthreads();

        if (cnt > 0.f) {
            const int f = idx2 & 1;
            const float h0 = hm[4 * b + f];
            const float h1 = hm[4 * b + 2 + f];
            const float CV = bs4[4 * b + 0], SV = bs4[4 * b + 1];
            const float CC = bs4[4 * b + 2], CS = bs4[4 * b + 3];
            const float SS = cnt - CC;
            float sumc, sqc;
            if (i2 == 0) {
                sumc = h0 * CV + h1 * SV;
                sqc  = 2.f * (h0 * xc[t] + h1 * xsv[t])
                     + h0 * h0 * CC + 2.f * h0 * h1 * CS + h1 * h1 * SS;
            } else {
                sumc = -h0 * SV + h1 * CV;
                sqc  = 2.f * (-h0 * xsv[t] + h1 * xc[t])
                     + h0 * h0 * SS - 2.f * h0 * h1 * CS + h1 * h1 * CC;
            }
            atomicAdd(&bnsum[t], sumc);
            atomicAdd(&bnsq[t], sqc);
        }
    }
    __threadfence();
    gg.sync();

    // ================= Phase 3: normalize + write out (all blocks) ============
    {
        float* mul_s = (float*)sm_u;
        float* add_s = mul_s + 256;
        {
            const float inv_n = 1.0f / (float)N_NODES;
            const float mu = bnsum[t] * inv_n;
            const float var = bnsq[t] * inv_n - mu * mu;
            const float inv = rsqrtf(var + BN_EPS);
            const float m = gamma[t] * inv;
            mul_s[t] = m;
            add_s[t] = beta[t] - mu * m;
        }
        __syncthreads();
        const int s = t >> 6;
        const int cg4 = t & 63;
        const float4 mm = *(const float4*)&mul_s[cg4 * 4];
        const float4 aa = *(const float4*)&add_s[cg4 * 4];

        for (int base = bid * 4; base < N_NODES; base += nblk * 4) {
            const int n = base + s;
            if (n < N_NODES) {
                const int g = batch[n];
                const float4 hmv = *(const float4*)(hmean + (size_t)g * C + cg4 * 4);
                union { unsigned int u; __hip_bfloat16 h[2]; } cs;
                cs.u = *(const unsigned int*)(csng + (size_t)n * 128 + cg4 * 2);
                const float cv = bf2f(cs.h[0]);
                const float sv = bf2f(cs.h[1]);
                const float4 xv = *(const float4*)(x + (size_t)n * C + cg4 * 4);
                float4 o;
                o.x = (xv.x + cv * hmv.x + sv * hmv.z) * mm.x + aa.x;
                o.y = (xv.y + cv * hmv.y + sv * hmv.w) * mm.y + aa.y;
                o.z = (xv.z - sv * hmv.x + cv * hmv.z) * mm.z + aa.z;
                o.w = (xv.w - sv * hmv.y + cv * hmv.w) * mm.w + aa.w;
                *(float4*)(out + (size_t)n * C + cg4 * 4) = o;
            }
        }
    }
}

// ===========================================================================
// Fallback path: verbatim round-2 kernels (known passing, 297 us).
// ===========================================================================
__global__ __launch_bounds__(256)
void k0_prep(const float* __restrict__ W1, const float* __restrict__ W2,
             __hip_bfloat16* __restrict__ Wt1, __hip_bfloat16* __restrict__ Wt2)
{
    const int t0 = threadIdx.x + blockIdx.x * 256;
    const int stride = gridDim.x * 256;
    for (int i = t0; i < 128 * 256; i += stride) {
        int n = i >> 8, k = i & 255;
        Wt1[n * WT1_LD + k] = __float2bfloat16(W1[k * 128 + n]);
    }
    for (int i = t0; i < 64 * 128; i += stride) {
        int n = i >> 7, k = i & 127;
        Wt2[n * WT2_LD + k] = __float2bfloat16(W2[k * 64 + n]);
    }
}

__global__ __launch_bounds__(256, 6)
void k1_angles_rot_pool(const float* __restrict__ x,
                        const int* __restrict__ batch,
                        const __hip_bfloat16* __restrict__ Wt1g,
                        const float* __restrict__ b1,
                        const __hip_bfloat16* __restrict__ Wt2g,
                        const float* __restrict__ b2,
                        float* __restrict__ gsums,
                        float* __restrict__ pbn,
                        __hip_bfloat16* __restrict__ csng)
{
    __shared__ __hip_bfloat16 xs[BLKN][XS_LD];
    __shared__ char sm_u[BLKN * WT2_LD * 2];
    __shared__ int gsh[BLKN];
    auto h1s = (__hip_bfloat16 (*)[WT2_LD])sm_u;
    auto csn = (__hip_bfloat16 (*)[132])sm_u;

    const int t = threadIdx.x;
    const int w = t >> 6;
    const int l = t & 63;
    const int lo = l & 15, quad = l >> 4;

    const short* w1base = (const short*)Wt1g + (w * 32 + lo) * WT1_LD + quad * 8;
    const int mw = w >> 1;
    const int nb0 = (w & 1) * 32;
    const short* w2base = (const short*)Wt2g + (nb0 + lo) * WT2_LD + quad * 8;
    const float bb1_0 = b1[w * 32 + lo];
    const float bb1_1 = b1[w * 32 + 16 + lo];
    const float bb2_0 = b2[nb0 + lo];
    const float bb2_1 = b2[nb0 + 16 + lo];

    const int pr = t >> 6;
    const int pc4 = (t & 63) * 4;

    const int c = t;
    const int b = c >> 2;
    const int idx2 = c & 3;
    float xc_a = 0.f, xs_a = 0.f, st = 0.f, rcnt = 0.f;
    float xm = 0.f, xq = 0.f;
    int gprev = -1;

#define FLUSH_G(gidx) do {                               \
        float* rec = gsums + (size_t)(gidx) * GREC;      \
        atomicAdd(&rec[c], xc_a);                        \
        atomicAdd(&rec[256 + c], xs_a);                  \
        atomicAdd(&rec[512 + c], st);                    \
        if (c == 0) atomicAdd(&rec[768], rcnt);          \
    } while (0)

    float4 pf[8];
    int pb = 0;
    {
        const int n0 = blockIdx.x * FB_ROWS;
        #pragma unroll
        for (int m = 0; m < 8; ++m)
            pf[m] = *(const float4*)(x + (size_t)(n0 + pr + m * 4) * C + pc4);
        if (t < BLKN) pb = batch[n0 + t];
    }

    for (int sub = 0; sub < FB_SUBT; ++sub) {
        const int n0 = blockIdx.x * FB_ROWS + sub * BLKN;
        if (n0 >= N_NODES) break;

        #pragma unroll
        for (int m = 0; m < 8; ++m) {
            bf4 pk;
            pk.x = __float2bfloat16(pf[m].x); pk.y = __float2bfloat16(pf[m].y);
            pk.z = __float2bfloat16(pf[m].z); pk.w = __float2bfloat16(pf[m].w);
            *(bf4*)&xs[pr + m * 4][pc4] = pk;
        }
        if (t < BLKN) gsh[t] = pb;

        const int n1 = n0 + BLKN;
        const bool more = (sub + 1 < FB_SUBT) && (n1 < N_NODES);
        if (more) {
            #pragma unroll
            for (int m = 0; m < 8; ++m)
                pf[m] = *(const float4*)(x + (size_t)(n1 + pr + m * 4) * C + pc4);
            if (t < BLKN) pb = batch[n1 + t];
        }
        __syncthreads();

        f32x4 acc1[2][2];
        #pragma unroll
        for (int mt = 0; mt < 2; ++mt) { acc1[mt][0] = (f32x4)0.f; acc1[mt][1] = (f32x4)0.f; }
        #pragma unroll
        for (int k = 0; k < 8; ++k) {
            bf16x8 bA = *(const bf16x8*)(w1base + k * 32);
            bf16x8 bB = *(const bf16x8*)(w1base + 16 * WT1_LD + k * 32);
            #pragma unroll
            for (int mt = 0; mt < 2; ++mt) {
                bf16x8 afr = *(const bf16x8*)&xs[mt * 16 + lo][k * 32 + quad * 8];
                acc1[mt][0] = __builtin_amdgcn_mfma_f32_16x16x32_bf16(afr, bA, acc1[mt][0], 0, 0, 0);
                acc1[mt][1] = __builtin_amdgcn_mfma_f32_16x16x32_bf16(afr, bB, acc1[mt][1], 0, 0, 0);
            }
        }
        #pragma unroll
        for (int nt = 0; nt < 2; ++nt) {
            const float bb = nt ? bb1_1 : bb1_0;
            #pragma unroll
            for (int mt = 0; mt < 2; ++mt) {
                #pragma unroll
                for (int r = 0; r < 4; ++r) {
                    float v = fast_gelu(acc1[mt][nt][r] + bb);
                    h1s[mt * 16 + quad * 4 + r][w * 32 + nt * 16 + lo] = __float2bfloat16(v);
                }
            }
        }
        __syncthreads();

        f32x4 acc2[2];
        acc2[0] = (f32x4)0.f; acc2[1] = (f32x4)0.f;
        #pragma unroll
        for (int k = 0; k < 4; ++k) {
            bf16x8 afr = *(const bf16x8*)&h1s[mw * 16 + lo][k * 32 + quad * 8];
            bf16x8 bA = *(const bf16x8*)(w2base + k * 32);
            bf16x8 bB = *(const bf16x8*)(w2base + 16 * WT2_LD + k * 32);
            acc2[0] = __builtin_amdgcn_mfma_f32_16x16x32_bf16(afr, bA, acc2[0], 0, 0, 0);
            acc2[1] = __builtin_amdgcn_mfma_f32_16x16x32_bf16(afr, bB, acc2[1], 0, 0, 0);
        }
        __syncthreads();

        #pragma unroll
        for (int nt = 0; nt < 2; ++nt) {
            const int col = nb0 + nt * 16 + lo;
            const float bb = nt ? bb2_1 : bb2_0;
            #pragma unroll
            for (int r = 0; r < 4; ++r) {
                float a = fast_tanh(acc2[nt][r] + bb);
                union { unsigned int u; __hip_bfloat16 h[2]; } p;
                p.h[0] = __float2bfloat16(__cosf(a));
                p.h[1] = __float2bfloat16(__sinf(a));
                *(unsigned int*)&csn[mw * 16 + quad * 4 + r][2 * col] = p.u;
            }
        }
        __syncthreads();

        #pragma unroll
        for (int m = 0; m < 4; ++m) {
            int idx = t + m * 256;
            int row = idx >> 5;
            int q = (idx & 31);
            uint2 v = *(const uint2*)&csn[row][q * 4];
            *(uint2*)(csng + (size_t)(n0 + row) * 128 + q * 4) = v;
        }

        #pragma unroll 8
        for (int r = 0; r < BLKN; ++r) {
            const int g = gsh[r];
            if (g != gprev) {
                if (gprev >= 0) FLUSH_G(gprev);
                xc_a = 0.f; xs_a = 0.f; st = 0.f; rcnt = 0.f;
                gprev = g;
            }
            const float xv = bf2f(xs[r][c]);
            union { unsigned int u; __hip_bfloat16 h[2]; } cs;
            cs.u = *(const unsigned int*)&csn[r][2 * b];
            const float cv = bf2f(cs.h[0]);
            const float sv = bf2f(cs.h[1]);
            xc_a += xv * cv;
            xs_a += xv * sv;
            xm += xv;
            xq += xv * xv;
            st += (idx2 == 0) ? cv : (idx2 == 1) ? sv : (idx2 == 2) ? cv * cv : cv * sv;
            rcnt += 1.f;
        }
        __syncthreads();
    }

    if (gprev >= 0) FLUSH_G(gprev);
#undef FLUSH_G
    pbn[(size_t)blockIdx.x * 512 + t] = xm;
    pbn[(size_t)blockIdx.x * 512 + 256 + t] = xq;
}

__global__ __launch_bounds__(256)
void k2_hmean_stats(const float* __restrict__ gsums,
                    const float* __restrict__ pbn,
                    const float* __restrict__ lin_w, const float* __restrict__ lin_b,
                    float* __restrict__ hmean,
                    float* __restrict__ bnsum, float* __restrict__ bnsq)
{
    __shared__ float xc[C], xsv[C], bs4[C], grot[C], hm[C];
    __shared__ float cnt_sh;
    const int g = blockIdx.x;
    const int t = threadIdx.x;

    {
        const int chunk = (FB_NBLK + NG - 1) / NG;   // 13
        const int r0 = g * chunk;
        const int r1 = (r0 + chunk < FB_NBLK) ? (r0 + chunk) : FB_NBLK;
        if (r0 < r1) {
            float a0 = 0.f, a1 = 0.f;
            for (int r = r0; r < r1; ++r) {
                a0 += pbn[(size_t)r * 512 + t];
                a1 += pbn[(size_t)r * 512 + 256 + t];
            }
            atomicAdd(&bnsum[t], a0);
            atomicAdd(&bnsq[t], a1);
        }
    }

    const float* rec = gsums + (size_t)g * GREC;
    xc[t]  = rec[t];
    xsv[t] = rec[256 + t];
    bs4[t] = rec[512 + t];
    if (t == 0) cnt_sh = rec[768];
    __syncthreads();

    const int b = t >> 2, idx2 = t & 3, i2 = idx2 >> 1;
    grot[t] = (i2 == 0) ? (xc[t] - xsv[t + 2]) : (xsv[t - 2] + xc[t]);
    __syncthreads();

    float a0 = 0.f, a1 = 0.f, a2 = 0.f, a3 = 0.f;
    #pragma unroll 4
    for (int k = 0; k < C; k += 4) {
        a0 += grot[k + 0] * lin_w[(size_t)(k + 0) * C + t];
        a1 += grot[k + 1] * lin_w[(size_t)(k + 1) * C + t];
        a2 += grot[k + 2] * lin_w[(size_t)(k + 2) * C + t];
        a3 += grot[k + 3] * lin_w[(size_t)(k + 3) * C + t];
    }
    const float cnt = cnt_sh;
    const float hv = (cnt > 0.f) ? ((a0 + a1 + a2 + a3) / cnt + lin_b[t]) : 0.f;
    hm[t] = hv;
    hmean[g * C + t] = hv;
    __syncthreads();

    if (cnt > 0.f) {
        const int f = idx2 & 1;
        const float h0 = hm[4 * b + f];
        const float h1 = hm[4 * b + 2 + f];
        const float CV = bs4[4 * b + 0], SV = bs4[4 * b + 1];
        const float CC = bs4[4 * b + 2], CS = bs4[4 * b + 3];
        const float SS = cnt - CC;
        float sumc, sqc;
        if (i2 == 0) {
            sumc = h0 * CV + h1 * SV;
            sqc  = 2.f * (h0 * xc[t] + h1 * xsv[t])
                 + h0 * h0 * CC + 2.f * h0 * h1 * CS + h1 * h1 * SS;
        } else {
            sumc = -h0 * SV + h1 * CV;
            sqc  = 2.f * (-h0 * xsv[t] + h1 * xc[t])
                 + h0 * h0 * SS - 2.f * h0 * h1 * CS + h1 * h1 * CC;
        }
        atomicAdd(&bnsum[t], sumc);
        atomicAdd(&bnsq[t], sqc);
    }
}

__global__ __launch_bounds__(256, 4)
void k4_fused(const float* __restrict__ x,
              const int* __restrict__ batch,
              const __hip_bfloat16* __restrict__ csng,
              const float* __restrict__ hmean,
              const float* __restrict__ bnsum, const float* __restrict__ bnsq,
              const float* __restrict__ gamma, const float* __restrict__ beta,
              float* __restrict__ out)
{
    __shared__ float mul_s[C], add_s[C];
    const int t = threadIdx.x;
    {
        const float inv_n = 1.0f / (float)N_NODES;
        const float mu = bnsum[t] * inv_n;
        const float var = bnsq[t] * inv_n - mu * mu;
        const float inv = rsqrtf(var + BN_EPS);
        const float m = gamma[t] * inv;
        mul_s[t] = m;
        add_s[t] = beta[t] - mu * m;
    }
    __syncthreads();
    const int s = t >> 6;
    const int cg4 = t & 63;
    const float4 mm = *(const float4*)&mul_s[cg4 * 4];
    const float4 aa = *(const float4*)&add_s[cg4 * 4];

    for (int base = blockIdx.x * 4; base < N_NODES; base += gridDim.x * 4) {
        const int n = base + s;
        if (n < N_NODES) {
            const int g = batch[n];
            const float4 hm = *(const float4*)(hmean + (size_t)g * C + cg4 * 4);
            union { unsigned int u; __hip_bfloat16 h[2]; } cs;
            cs.u = *(const unsigned int*)(csng + (size_t)n * 128 + cg4 * 2);
            const float cv = bf2f(cs.h[0]);
            const float sv = bf2f(cs.h[1]);
            const float4 xv = *(const float4*)(x + (size_t)n * C + cg4 * 4);
            float4 o;
            o.x = (xv.x + cv * hm.x + sv * hm.z) * mm.x + aa.x;
            o.y = (xv.y + cv * hm.y + sv * hm.w) * mm.y + aa.y;
            o.z = (xv.z - sv * hm.x + cv * hm.z) * mm.z + aa.z;
            o.w = (xv.w - sv * hm.y + cv * hm.w) * mm.w + aa.w;
            *(float4*)(out + (size_t)n * C + cg4 * 4) = o;
        }
    }
}

// ---------------------------------------------------------------------------
extern "C" void kernel_launch(void* const* d_in, const int* in_sizes, int n_in,
                              void* d_out, int out_size, void* d_ws, size_t ws_size,
                              hipStream_t stream)
{
    const float* x      = (const float*)d_in[0];
    // d_in[1] = edge_index (unused, num_gnn == 0)
    const int* batch    = (const int*)d_in[2];
    const float* W1     = (const float*)d_in[3];
    const float* b1     = (const float*)d_in[4];
    const float* W2     = (const float*)d_in[5];
    const float* b2     = (const float*)d_in[6];
    const float* lin_w  = (const float*)d_in[7];
    const float* lin_b  = (const float*)d_in[8];
    const float* gamma  = (const float*)d_in[9];
    const float* beta   = (const float*)d_in[10];
    float* ws  = (float*)d_ws;
    float* out = (float*)d_out;

    // One-time, stream-free occupancy gate for the cooperative path.
    // Mirrors the runtime's own cooperative-launch validation so we never
    // issue a launch that would be rejected (round-3 failure mode).
    static int coop_blocks = -2;
    if (coop_blocks == -2) {
        int nb = 0, dev = 0, ncu = 0;
        hipError_t e = hipOccupancyMaxActiveBlocksPerMultiprocessor(
            &nb, (const void*)fused, 256, 0);
        if (e == hipSuccess && hipGetDevice(&dev) == hipSuccess) {
            hipDeviceProp_t prop;
            if (hipGetDeviceProperties(&prop, dev) == hipSuccess)
                ncu = prop.multiProcessorCount;
        }
        long total = (long)nb * (long)ncu;
        if (total >= 512) {
            if (total > COOP_MAX) total = COOP_MAX;
            coop_blocks = (int)(total & ~127L);   // multiple of 128
        } else {
            coop_blocks = -1;                     // fallback path
        }
    }

    if (coop_blocks > 0) {
        void* args[] = {(void*)&x, (void*)&batch, (void*)&W1, (void*)&b1,
                        (void*)&W2, (void*)&b2, (void*)&lin_w, (void*)&lin_b,
                        (void*)&gamma, (void*)&beta, (void*)&ws, (void*)&out};
        hipError_t e = hipLaunchCooperativeKernel((const void*)fused,
                                                  dim3(coop_blocks), dim3(256),
                                                  args, 0, stream);
        if (e == hipSuccess) return;
        (void)hipGetLastError();      // clear error state, fall through
        coop_blocks = -1;             // never try again
    }

    // -------- fallback: round-2 multi-kernel path (known good) --------
    float* gsums = ws + OFF_GSUMS;
    float* bnsum = ws + OFF_BNSUM;
    float* bnsq  = ws + OFF_BNSQ;
    float* hmean = ws + OFF_HMEAN;
    __hip_bfloat16* Wt1  = (__hip_bfloat16*)(ws + OFF_WT1);
    __hip_bfloat16* Wt2  = (__hip_bfloat16*)(ws + OFF_WT2);
    __hip_bfloat16* csng = (__hip_bfloat16*)(ws + OFF_CSN);
    float* pbn   = ws + OFF_PBN;

    hipMemsetAsync(gsums, 0, ZERO_FLOATS * sizeof(float), stream);
    k0_prep<<<32, 256, 0, stream>>>(W1, W2, Wt1, Wt2);
    k1_angles_rot_pool<<<FB_NBLK, 256, 0, stream>>>(x, batch, Wt1, b1, Wt2, b2,
                                                    gsums, pbn, csng);
    k2_hmean_stats<<<NG, 256, 0, stream>>>(gsums, pbn, lin_w, lin_b, hmean, bnsum, bnsq);
    k4_fused<<<2048, 256, 0, stream>>>(x, batch, csng, hmean, bnsum, bnsq,
                                       gamma, beta, out);
}

// Round 5
// 317.449 us; speedup vs baseline: 1.9145x; 1.9145x over previous
//
#include <hip/hip_runtime.h>
#include <hip/hip_bf16.h>
#include <math.h>

#define N_NODES 100000
#define C 256
#define NB 64
#define H1D 128
#define NG 128
#define BN_EPS 1e-5f

#define BLKN 32                           // rows per wave-subtile
#define NSUB (N_NODES / BLKN)             // 3125 wave-tasks, exact
#define NPART NSUB                        // pbn rows (one per wave-task)

// per-graph record: XC[256] | XS[256] | BS[256] (b*4+{CV,SV,CC,CS}) | cnt
#define GREC 769

// ws layout (float offsets)
#define OFF_GSUMS 0
#define OFF_BNSUM (NG * GREC)            // 98432
#define OFF_BNSQ  (OFF_BNSUM + 256)      // 98688
#define ZERO_FLOATS (OFF_BNSQ + 256)     // 98944 floats zeroed in k0
#define OFF_HMEAN ZERO_FLOATS            // 98944
#define OFF_WT1   (OFF_HMEAN + NG * C)   // +32768
#define OFF_WT2   (OFF_WT1 + 16896)
#define OFF_CSN   (OFF_WT2 + 4352)       // N*128 bf16 = 6.4M floats
#define OFF_PBN   (OFF_CSN + N_NODES * 64)   // NPART x 512 fp32 (6.4 MB)

#define WT1_LD 264   // bf16 stride of Wt1 in global (16B-aligned rows)
#define WT2_LD 136
// h1s LDS stride = WT2_LD (136 bf16): row shift 272B = 68 banks -> spread

typedef __attribute__((ext_vector_type(8))) short bf16x8;
typedef __attribute__((ext_vector_type(4))) float f32x4;

__device__ __forceinline__ float bf2f(__hip_bfloat16 h) { return __bfloat162float(h); }

__device__ __forceinline__ float fast_tanh(float y) {
    // exact identity, fast exp (v_exp); y bounded (~|y|<6) in this net
    float e = __expf(2.f * y);
    return 1.f - 2.f / (e + 1.f);
}
__device__ __forceinline__ float fast_gelu(float v) {
    // tanh-form GELU, max abs err ~1.5e-3 vs exact-erf (threshold 0.11)
    float u = 0.7978845608f * (v + 0.044715f * v * v * v);
    return 0.5f * v * (1.f + fast_tanh(u));
}

__device__ __forceinline__ bf16x8 pack8(float4 a, float4 b) {
    union { bf16x8 v; __hip_bfloat16 h[8]; } u;
    u.h[0] = __float2bfloat16(a.x); u.h[1] = __float2bfloat16(a.y);
    u.h[2] = __float2bfloat16(a.z); u.h[3] = __float2bfloat16(a.w);
    u.h[4] = __float2bfloat16(b.x); u.h[5] = __float2bfloat16(b.y);
    u.h[6] = __float2bfloat16(b.z); u.h[7] = __float2bfloat16(b.w);
    return u.v;
}

// ---------------------------------------------------------------------------
// K0: zero the stats region (replaces the hipMemsetAsync dispatch) and
//     transpose+convert weights to bf16 [out_ch][in_ch] layout for MFMA B-frags
// ---------------------------------------------------------------------------
__global__ __launch_bounds__(256)
void k0_prep(const float* __restrict__ W1, const float* __restrict__ W2,
             float* __restrict__ ws,
             __hip_bfloat16* __restrict__ Wt1, __hip_bfloat16* __restrict__ Wt2)
{
    const int t0 = threadIdx.x + blockIdx.x * 256;
    const int stride = gridDim.x * 256;          // 131072
    for (int i = t0; i < ZERO_FLOATS; i += stride)
        ws[i] = 0.f;
    for (int i = t0; i < 128 * 256; i += stride) {
        int n = i >> 8, k = i & 255;
        Wt1[n * WT1_LD + k] = __float2bfloat16(W1[k * 128 + n]);
    }
    for (int i = t0; i < 64 * 128; i += stride) {
        int n = i >> 7, k = i & 127;
        Wt2[n * WT2_LD + k] = __float2bfloat16(W2[k * 64 + n]);
    }
}

// ---------------------------------------------------------------------------
// K1 (wave-autonomous, barrier-free): one 64-lane wave owns one 32-row
// subtile end-to-end. No __syncthreads anywhere: the h1 transpose and csn
// buffer are same-wave LDS traffic (hardware-ordered via lgkmcnt).
//   GEMM1 A-frags load x directly from global (no LDS x-tile) -> 8.8 KB
//   LDS/block -> ~16-18 one-wave blocks resident/CU, all independent.
//   GEMM1(32x256@256x128) -> GELU -> h1s LDS -> GEMM2(32x128@128x64)
//   -> tanh/sincos -> csn LDS -> csng global; Phase D re-reads x (L1/L2-hot)
//   and accumulates per-graph stats (atomics per segment) + BN partials (pbn).
// ---------------------------------------------------------------------------
__global__ __launch_bounds__(64, 4)
void k1_wave(const float* __restrict__ x,
             const int* __restrict__ batch,
             const __hip_bfloat16* __restrict__ Wt1g,
             const float* __restrict__ b1,
             const __hip_bfloat16* __restrict__ Wt2g,
             const float* __restrict__ b2,
             float* __restrict__ gsums,
             float* __restrict__ pbn,
             __hip_bfloat16* __restrict__ csng)
{
    __shared__ __hip_bfloat16 h1s[BLKN][WT2_LD];   // 8704 B, csn aliased
    __shared__ int gsh[BLKN];                      // 128 B
    auto csn = (__hip_bfloat16 (*)[132])&h1s[0][0];  // [2c]=cos,[2c+1]=sin

    const int l = threadIdx.x;            // 0..63
    const int lo = l & 15, quad = l >> 4;
    const int wid = blockIdx.x;           // 0..3124
    const int n0 = wid * BLKN;

    if (l < BLKN) gsh[l] = batch[n0 + l];

    // ---- GEMM1: h1 = x[32,256] @ W1[256,128]; 2 Mtiles x 8 Ntiles x 8 K ----
    f32x4 acc1[2][8];
    #pragma unroll
    for (int nt = 0; nt < 8; ++nt) { acc1[0][nt] = (f32x4)0.f; acc1[1][nt] = (f32x4)0.f; }

    const float* xr0 = x + (size_t)(n0 + lo) * C + quad * 8;
    const short* w1row = (const short*)Wt1g + lo * WT1_LD + quad * 8;
    #pragma unroll
    for (int k = 0; k < 8; ++k) {
        float4 u00 = *(const float4*)(xr0 + k * 32);
        float4 u01 = *(const float4*)(xr0 + k * 32 + 4);
        float4 u10 = *(const float4*)(xr0 + 16 * C + k * 32);
        float4 u11 = *(const float4*)(xr0 + 16 * C + k * 32 + 4);
        bf16x8 a0 = pack8(u00, u01);
        bf16x8 a1 = pack8(u10, u11);
        #pragma unroll
        for (int nt = 0; nt < 8; ++nt) {
            bf16x8 bB = *(const bf16x8*)(w1row + nt * 16 * WT1_LD + k * 32);
            acc1[0][nt] = __builtin_amdgcn_mfma_f32_16x16x32_bf16(a0, bB, acc1[0][nt], 0, 0, 0);
            acc1[1][nt] = __builtin_amdgcn_mfma_f32_16x16x32_bf16(a1, bB, acc1[1][nt], 0, 0, 0);
        }
    }

    // ---- bias + fast GELU -> h1s (row = mt*16+quad*4+r, col = nt*16+lo) ----
    #pragma unroll
    for (int nt = 0; nt < 8; ++nt) {
        const float bb = b1[nt * 16 + lo];
        #pragma unroll
        for (int mt = 0; mt < 2; ++mt) {
            #pragma unroll
            for (int r = 0; r < 4; ++r) {
                float v = fast_gelu(acc1[mt][nt][r] + bb);
                h1s[mt * 16 + quad * 4 + r][nt * 16 + lo] = __float2bfloat16(v);
            }
        }
    }

    // ---- GEMM2: ang = h1[32,128] @ W2[128,64]; 2 Mtiles x 4 Ntiles x 4 K ----
    f32x4 acc2[2][4];
    #pragma unroll
    for (int nt = 0; nt < 4; ++nt) { acc2[0][nt] = (f32x4)0.f; acc2[1][nt] = (f32x4)0.f; }
    const short* w2row = (const short*)Wt2g + lo * WT2_LD + quad * 8;
    #pragma unroll
    for (int k = 0; k < 4; ++k) {
        bf16x8 af0 = *(const bf16x8*)&h1s[lo][k * 32 + quad * 8];
        bf16x8 af1 = *(const bf16x8*)&h1s[16 + lo][k * 32 + quad * 8];
        #pragma unroll
        for (int nt = 0; nt < 4; ++nt) {
            bf16x8 bB = *(const bf16x8*)(w2row + nt * 16 * WT2_LD + k * 32);
            acc2[0][nt] = __builtin_amdgcn_mfma_f32_16x16x32_bf16(af0, bB, acc2[0][nt], 0, 0, 0);
            acc2[1][nt] = __builtin_amdgcn_mfma_f32_16x16x32_bf16(af1, bB, acc2[1][nt], 0, 0, 0);
        }
    }

    // ---- fast tanh -> hw sincos -> interleaved csn (aliases h1s; same-wave
    //      DS ordering guarantees all h1s reads above complete first) ----
    #pragma unroll
    for (int nt = 0; nt < 4; ++nt) {
        const int col = nt * 16 + lo;
        const float bb = b2[col];
        #pragma unroll
        for (int mt = 0; mt < 2; ++mt) {
            #pragma unroll
            for (int r = 0; r < 4; ++r) {
                float a = fast_tanh(acc2[mt][nt][r] + bb);
                union { unsigned int u; __hip_bfloat16 h[2]; } p;
                p.h[0] = __float2bfloat16(__cosf(a));
                p.h[1] = __float2bfloat16(__sinf(a));
                *(unsigned int*)&csn[mt * 16 + quad * 4 + r][2 * col] = p.u;
            }
        }
    }

    // ---- coalesced global write of interleaved cos/sin (8B per lane) ----
    #pragma unroll
    for (int m = 0; m < 16; ++m) {
        int idx = l + m * 64;             // 0..1023 : 32 rows x 32 qwords
        int row = idx >> 5;
        int q = idx & 31;
        uint2 v = *(const uint2*)&csn[row][q * 4];
        *(uint2*)(csng + (size_t)(n0 + row) * 128 + q * 4) = v;
    }

    // ---- Phase D: per-graph stats; lane = bundle l, channels 4l..4l+3 ----
    const int c0 = 4 * l;
    float xc0 = 0.f, xc1 = 0.f, xc2 = 0.f, xc3 = 0.f;
    float xs0 = 0.f, xs1 = 0.f, xs2 = 0.f, xs3 = 0.f;
    float xm0 = 0.f, xm1 = 0.f, xm2 = 0.f, xm3 = 0.f;
    float xq0 = 0.f, xq1 = 0.f, xq2 = 0.f, xq3 = 0.f;
    float stc = 0.f, sts = 0.f, stcc = 0.f, stcs = 0.f, rcnt = 0.f;
    int gprev = -1;

#define FLUSH_G(gidx) do {                                            \
        float* rec = gsums + (size_t)(gidx) * GREC;                   \
        atomicAdd(&rec[c0 + 0], xc0); atomicAdd(&rec[c0 + 1], xc1);   \
        atomicAdd(&rec[c0 + 2], xc2); atomicAdd(&rec[c0 + 3], xc3);   \
        atomicAdd(&rec[256 + c0 + 0], xs0); atomicAdd(&rec[256 + c0 + 1], xs1); \
        atomicAdd(&rec[256 + c0 + 2], xs2); atomicAdd(&rec[256 + c0 + 3], xs3); \
        atomicAdd(&rec[512 + c0 + 0], stc); atomicAdd(&rec[512 + c0 + 1], sts); \
        atomicAdd(&rec[512 + c0 + 2], stcc); atomicAdd(&rec[512 + c0 + 3], stcs); \
        if (l == 0) atomicAdd(&rec[768], rcnt);                       \
    } while (0)

    #pragma unroll 8
    for (int r = 0; r < BLKN; ++r) {
        const int g = gsh[r];
        if (g != gprev) {                 // wave-uniform branch
            if (gprev >= 0) FLUSH_G(gprev);
            xc0 = xc1 = xc2 = xc3 = 0.f;
            xs0 = xs1 = xs2 = xs3 = 0.f;
            stc = sts = stcc = stcs = 0.f;
            rcnt = 0.f;
            gprev = g;
        }
        const float4 xv = *(const float4*)(x + (size_t)(n0 + r) * C + c0);
        union { unsigned int u; __hip_bfloat16 h[2]; } cs;
        cs.u = *(const unsigned int*)&csn[r][2 * l];
        const float cv = bf2f(cs.h[0]);
        const float sv = bf2f(cs.h[1]);
        xc0 += xv.x * cv; xc1 += xv.y * cv; xc2 += xv.z * cv; xc3 += xv.w * cv;
        xs0 += xv.x * sv; xs1 += xv.y * sv; xs2 += xv.z * sv; xs3 += xv.w * sv;
        xm0 += xv.x; xm1 += xv.y; xm2 += xv.z; xm3 += xv.w;
        xq0 += xv.x * xv.x; xq1 += xv.y * xv.y; xq2 += xv.z * xv.z; xq3 += xv.w * xv.w;
        stc += cv; sts += sv; stcc += cv * cv; stcs += cv * sv;
        rcnt += 1.f;
    }
    if (gprev >= 0) FLUSH_G(gprev);
#undef FLUSH_G

    // BN partials: non-atomic, coalesced float4; reduced in K2's prologue
    float4 m4; m4.x = xm0; m4.y = xm1; m4.z = xm2; m4.w = xm3;
    float4 q4; q4.x = xq0; q4.y = xq1; q4.z = xq2; q4.w = xq3;
    *(float4*)&pbn[(size_t)wid * 512 + c0] = m4;
    *(float4*)&pbn[(size_t)wid * 512 + 256 + c0] = q4;
}

// ---------------------------------------------------------------------------
// K2: prologue: block g reduces a contiguous r-chunk of pbn over ALL channels
//     (coalesced wave reads), one atomicAdd per channel per block.
//     Then per graph: reconstruct rotated pool sums, hmean = (grot@lin_w)/cnt+b;
//     add closed-form BN contributions of o = x + R^T hmean to bnsum/bnsq.
// ---------------------------------------------------------------------------
__global__ __launch_bounds__(256)
void k2_hmean_stats(const float* __restrict__ gsums,
                    const float* __restrict__ pbn,
                    const float* __restrict__ lin_w, const float* __restrict__ lin_b,
                    float* __restrict__ hmean,
                    float* __restrict__ bnsum, float* __restrict__ bnsq)
{
    __shared__ float xc[C], xsv[C], bs4[C], grot[C], hm[C];
    __shared__ float cnt_sh;
    const int g = blockIdx.x;
    const int t = threadIdx.x;

    {
        const int chunk = (NPART + NG - 1) / NG;   // 25
        const int r0 = g * chunk;
        const int r1 = (r0 + chunk < NPART) ? (r0 + chunk) : NPART;
        if (r0 < r1) {
            float a0 = 0.f, a1 = 0.f;
            for (int r = r0; r < r1; ++r) {
                a0 += pbn[(size_t)r * 512 + t];
                a1 += pbn[(size_t)r * 512 + 256 + t];
            }
            atomicAdd(&bnsum[t], a0);
            atomicAdd(&bnsq[t], a1);
        }
    }

    const float* rec = gsums + (size_t)g * GREC;
    xc[t]  = rec[t];
    xsv[t] = rec[256 + t];
    bs4[t] = rec[512 + t];
    if (t == 0) cnt_sh = rec[768];
    __syncthreads();

    const int b = t >> 2, idx2 = t & 3, i2 = idx2 >> 1;
    // rotated pool sum: c0=4b+f pairs with c1=4b+2+f
    grot[t] = (i2 == 0) ? (xc[t] - xsv[t + 2]) : (xsv[t - 2] + xc[t]);
    __syncthreads();

    float a0 = 0.f, a1 = 0.f, a2 = 0.f, a3 = 0.f;
    #pragma unroll 4
    for (int k = 0; k < C; k += 4) {
        a0 += grot[k + 0] * lin_w[(size_t)(k + 0) * C + t];
        a1 += grot[k + 1] * lin_w[(size_t)(k + 1) * C + t];
        a2 += grot[k + 2] * lin_w[(size_t)(k + 2) * C + t];
        a3 += grot[k + 3] * lin_w[(size_t)(k + 3) * C + t];
    }
    const float cnt = cnt_sh;
    const float hv = (cnt > 0.f) ? ((a0 + a1 + a2 + a3) / cnt + lin_b[t]) : 0.f;
    hm[t] = hv;
    hmean[g * C + t] = hv;
    __syncthreads();

    if (cnt > 0.f) {
        const int f = idx2 & 1;
        const float h0 = hm[4 * b + f];
        const float h1 = hm[4 * b + 2 + f];
        const float CV = bs4[4 * b + 0], SV = bs4[4 * b + 1];
        const float CC = bs4[4 * b + 2], CS = bs4[4 * b + 3];
        const float SS = cnt - CC;       // cv^2+sv^2 = 1 (bf16 eps negligible)
        float sumc, sqc;
        if (i2 == 0) {
            sumc = h0 * CV + h1 * SV;
            sqc  = 2.f * (h0 * xc[t] + h1 * xsv[t])
                 + h0 * h0 * CC + 2.f * h0 * h1 * CS + h1 * h1 * SS;
        } else {
            sumc = -h0 * SV + h1 * CV;
            sqc  = 2.f * (-h0 * xsv[t] + h1 * xc[t])
                 + h0 * h0 * SS - 2.f * h0 * h1 * CS + h1 * h1 * CC;
        }
        atomicAdd(&bnsum[t], sumc);
        atomicAdd(&bnsq[t], sqc);
    }
}

// ---------------------------------------------------------------------------
// K4: o = x + R^T hmean[batch[n]], normalized, single output pass.
// ---------------------------------------------------------------------------
__global__ __launch_bounds__(256, 4)
void k4_fused(const float* __restrict__ x,
              const int* __restrict__ batch,
              const __hip_bfloat16* __restrict__ csng,
              const float* __restrict__ hmean,
              const float* __restrict__ bnsum, const float* __restrict__ bnsq,
              const float* __restrict__ gamma, const float* __restrict__ beta,
              float* __restrict__ out)
{
    __shared__ float mul_s[C], add_s[C];
    const int t = threadIdx.x;
    {
        const float inv_n = 1.0f / (float)N_NODES;
        const float mu = bnsum[t] * inv_n;
        const float var = bnsq[t] * inv_n - mu * mu;
        const float inv = rsqrtf(var + BN_EPS);
        const float m = gamma[t] * inv;
        mul_s[t] = m;
        add_s[t] = beta[t] - mu * m;
    }
    __syncthreads();
    const int s = t >> 6;
    const int cg4 = t & 63;
    const float4 mm = *(const float4*)&mul_s[cg4 * 4];
    const float4 aa = *(const float4*)&add_s[cg4 * 4];

    for (int base = blockIdx.x * 4; base < N_NODES; base += gridDim.x * 4) {
        const int n = base + s;
        if (n < N_NODES) {
            const int g = batch[n];
            const float4 hm = *(const float4*)(hmean + (size_t)g * C + cg4 * 4);
            union { unsigned int u; __hip_bfloat16 h[2]; } cs;
            cs.u = *(const unsigned int*)(csng + (size_t)n * 128 + cg4 * 2);
            const float cv = bf2f(cs.h[0]);
            const float sv = bf2f(cs.h[1]);
            const float4 xv = *(const float4*)(x + (size_t)n * C + cg4 * 4);
            float4 o;
            o.x = (xv.x + cv * hm.x + sv * hm.z) * mm.x + aa.x;
            o.y = (xv.y + cv * hm.y + sv * hm.w) * mm.y + aa.y;
            o.z = (xv.z - sv * hm.x + cv * hm.z) * mm.z + aa.z;
            o.w = (xv.w - sv * hm.y + cv * hm.w) * mm.w + aa.w;
            *(float4*)(out + (size_t)n * C + cg4 * 4) = o;
        }
    }
}

// ---------------------------------------------------------------------------
extern "C" void kernel_launch(void* const* d_in, const int* in_sizes, int n_in,
                              void* d_out, int out_size, void* d_ws, size_t ws_size,
                              hipStream_t stream)
{
    const float* x      = (const float*)d_in[0];
    // d_in[1] = edge_index (unused, num_gnn == 0)
    const int* batch    = (const int*)d_in[2];
    const float* W1     = (const float*)d_in[3];
    const float* b1     = (const float*)d_in[4];
    const float* W2     = (const float*)d_in[5];
    const float* b2     = (const float*)d_in[6];
    const float* lin_w  = (const float*)d_in[7];
    const float* lin_b  = (const float*)d_in[8];
    const float* gamma  = (const float*)d_in[9];
    const float* beta   = (const float*)d_in[10];

    float* ws    = (float*)d_ws;
    float* gsums = ws + OFF_GSUMS;
    float* bnsum = ws + OFF_BNSUM;
    float* bnsq  = ws + OFF_BNSQ;
    float* hmean = ws + OFF_HMEAN;
    __hip_bfloat16* Wt1  = (__hip_bfloat16*)(ws + OFF_WT1);
    __hip_bfloat16* Wt2  = (__hip_bfloat16*)(ws + OFF_WT2);
    __hip_bfloat16* csng = (__hip_bfloat16*)(ws + OFF_CSN);
    float* pbn   = ws + OFF_PBN;
    float* out   = (float*)d_out;

    k0_prep<<<512, 256, 0, stream>>>(W1, W2, ws, Wt1, Wt2);
    k1_wave<<<NSUB, 64, 0, stream>>>(x, batch, Wt1, b1, Wt2, b2,
                                     gsums, pbn, csng);
    k2_hmean_stats<<<NG, 256, 0, stream>>>(gsums, pbn, lin_w, lin_b, hmean, bnsum, bnsq);
    k4_fused<<<2048, 256, 0, stream>>>(x, batch, csng, hmean, bnsum, bnsq,
                                       gamma, beta, out);
}

// Round 6
// 315.468 us; speedup vs baseline: 1.9265x; 1.0063x over previous
//
#include <hip/hip_runtime.h>
#include <hip/hip_bf16.h>
#include <math.h>

#define N_NODES 100000
#define C 256
#define NB 64
#define H1D 128
#define NG 128
#define BN_EPS 1e-5f

#define BLKN 32                           // rows per wave-subtile
#define NSUB (N_NODES / BLKN)             // 3125 wave-tasks, exact
#define NPART NSUB                        // pbn rows (one per wave-task)
#define WPB 4                             // independent waves per block
#define NBLK1 ((NSUB + WPB - 1) / WPB)    // 782 blocks

// per-graph record: XC[256] | XS[256] | BS[256] (b*4+{CV,SV,CC,CS}) | cnt
#define GREC 769

// ws layout (float offsets)
#define OFF_GSUMS 0
#define OFF_BNSUM (NG * GREC)            // 98432
#define OFF_BNSQ  (OFF_BNSUM + 256)      // 98688
#define ZERO_FLOATS (OFF_BNSQ + 256)     // 98944 floats zeroed in k0
#define OFF_HMEAN ZERO_FLOATS            // 98944
#define OFF_WT1   (OFF_HMEAN + NG * C)   // +32768
#define OFF_WT2   (OFF_WT1 + 16896)
#define OFF_CSN   (OFF_WT2 + 4352)       // N*128 bf16 = 6.4M floats
#define OFF_PBN   (OFF_CSN + N_NODES * 64)   // NPART x 512 fp32 (6.4 MB)

#define WT1_LD 264   // bf16 stride of Wt1 in global (16B-aligned rows)
#define WT2_LD 136
// h1s LDS stride = WT2_LD (136 bf16): row shift 272B = 68 banks -> spread

typedef __attribute__((ext_vector_type(8))) short bf16x8;
typedef __attribute__((ext_vector_type(4))) float f32x4;

__device__ __forceinline__ float bf2f(__hip_bfloat16 h) { return __bfloat162float(h); }

__device__ __forceinline__ float fast_tanh(float y) {
    // exact identity, fast exp (v_exp); y bounded (~|y|<6) in this net
    float e = __expf(2.f * y);
    return 1.f - 2.f / (e + 1.f);
}
__device__ __forceinline__ float fast_gelu(float v) {
    // tanh-form GELU, max abs err ~1.5e-3 vs exact-erf (threshold 0.11)
    float u = 0.7978845608f * (v + 0.044715f * v * v * v);
    return 0.5f * v * (1.f + fast_tanh(u));
}

__device__ __forceinline__ bf16x8 pack8(float4 a, float4 b) {
    union { bf16x8 v; __hip_bfloat16 h[8]; } u;
    u.h[0] = __float2bfloat16(a.x); u.h[1] = __float2bfloat16(a.y);
    u.h[2] = __float2bfloat16(a.z); u.h[3] = __float2bfloat16(a.w);
    u.h[4] = __float2bfloat16(b.x); u.h[5] = __float2bfloat16(b.y);
    u.h[6] = __float2bfloat16(b.z); u.h[7] = __float2bfloat16(b.w);
    return u.v;
}

// ---------------------------------------------------------------------------
// K0: zero the stats region (replaces the hipMemsetAsync dispatch) and
//     transpose+convert weights to bf16 [out_ch][in_ch] layout for MFMA B-frags
// ---------------------------------------------------------------------------
__global__ __launch_bounds__(256)
void k0_prep(const float* __restrict__ W1, const float* __restrict__ W2,
             float* __restrict__ ws,
             __hip_bfloat16* __restrict__ Wt1, __hip_bfloat16* __restrict__ Wt2)
{
    const int t0 = threadIdx.x + blockIdx.x * 256;
    const int stride = gridDim.x * 256;          // 131072
    for (int i = t0; i < ZERO_FLOATS; i += stride)
        ws[i] = 0.f;
    for (int i = t0; i < 128 * 256; i += stride) {
        int n = i >> 8, k = i & 255;
        Wt1[n * WT1_LD + k] = __float2bfloat16(W1[k * 128 + n]);
    }
    for (int i = t0; i < 64 * 128; i += stride) {
        int n = i >> 7, k = i & 127;
        Wt2[n * WT2_LD + k] = __float2bfloat16(W2[k * 64 + n]);
    }
}

// ---------------------------------------------------------------------------
// K1: 4 INDEPENDENT waves per 256-thread block (fixes the round-5 occupancy
// collapse: 1-wave workgroups packed only ~8/CU; 4-wave groups at 35.3 KB LDS
// pack 4 blocks/CU = 16 waves/CU). Still ZERO __syncthreads: each wave owns
// its own LDS slice, h1/csn traffic is same-wave (lgkmcnt-ordered).
//   Per wave: GEMM1(32x256@256x128) w/ x A-frags straight from global ->
//   GELU -> h1s LDS -> GEMM2(32x128@128x64) -> tanh/sincos -> csn LDS ->
//   csng global; Phase D re-reads x and accumulates per-graph stats
//   (atomics per graph segment) + BN partials (pbn, non-atomic).
// ---------------------------------------------------------------------------
__global__ __launch_bounds__(256, 4)
void k1_wave(const float* __restrict__ x,
             const int* __restrict__ batch,
             const __hip_bfloat16* __restrict__ Wt1g,
             const float* __restrict__ b1,
             const __hip_bfloat16* __restrict__ Wt2g,
             const float* __restrict__ b2,
             float* __restrict__ gsums,
             float* __restrict__ pbn,
             __hip_bfloat16* __restrict__ csng)
{
    __shared__ __hip_bfloat16 h1s4[WPB][BLKN][WT2_LD];   // 4 x 8704 B
    __shared__ int gsh4[WPB][BLKN];                      // 4 x 128 B -> 35328 B

    const int t = threadIdx.x;
    const int wv = t >> 6;                // wave 0..3 (independent tasks)
    const int l = t & 63;
    const int lo = l & 15, quad = l >> 4;
    const int wid = blockIdx.x * WPB + wv;
    if (wid >= NSUB) return;              // wave-uniform (no barriers anywhere)
    const int n0 = wid * BLKN;

    auto h1s = h1s4[wv];
    auto csn = (__hip_bfloat16 (*)[132])&h1s4[wv][0][0];  // [2c]=cos,[2c+1]=sin
    int* gsh = gsh4[wv];

    if (l < BLKN) gsh[l] = batch[n0 + l];

    // ---- GEMM1: h1 = x[32,256] @ W1[256,128]; 2 Mtiles x 8 Ntiles x 8 K ----
    f32x4 acc1[2][8];
    #pragma unroll
    for (int nt = 0; nt < 8; ++nt) { acc1[0][nt] = (f32x4)0.f; acc1[1][nt] = (f32x4)0.f; }

    const float* xr0 = x + (size_t)(n0 + lo) * C + quad * 8;
    const short* w1row = (const short*)Wt1g + lo * WT1_LD + quad * 8;
    #pragma unroll
    for (int k = 0; k < 8; ++k) {
        float4 u00 = *(const float4*)(xr0 + k * 32);
        float4 u01 = *(const float4*)(xr0 + k * 32 + 4);
        float4 u10 = *(const float4*)(xr0 + 16 * C + k * 32);
        float4 u11 = *(const float4*)(xr0 + 16 * C + k * 32 + 4);
        bf16x8 a0 = pack8(u00, u01);
        bf16x8 a1 = pack8(u10, u11);
        #pragma unroll
        for (int nt = 0; nt < 8; ++nt) {
            bf16x8 bB = *(const bf16x8*)(w1row + nt * 16 * WT1_LD + k * 32);
            acc1[0][nt] = __builtin_amdgcn_mfma_f32_16x16x32_bf16(a0, bB, acc1[0][nt], 0, 0, 0);
            acc1[1][nt] = __builtin_amdgcn_mfma_f32_16x16x32_bf16(a1, bB, acc1[1][nt], 0, 0, 0);
        }
    }

    // ---- bias + fast GELU -> h1s (row = mt*16+quad*4+r, col = nt*16+lo) ----
    #pragma unroll
    for (int nt = 0; nt < 8; ++nt) {
        const float bb = b1[nt * 16 + lo];
        #pragma unroll
        for (int mt = 0; mt < 2; ++mt) {
            #pragma unroll
            for (int r = 0; r < 4; ++r) {
                float v = fast_gelu(acc1[mt][nt][r] + bb);
                h1s[mt * 16 + quad * 4 + r][nt * 16 + lo] = __float2bfloat16(v);
            }
        }
    }

    // ---- GEMM2: ang = h1[32,128] @ W2[128,64]; 2 Mtiles x 4 Ntiles x 4 K ----
    f32x4 acc2[2][4];
    #pragma unroll
    for (int nt = 0; nt < 4; ++nt) { acc2[0][nt] = (f32x4)0.f; acc2[1][nt] = (f32x4)0.f; }
    const short* w2row = (const short*)Wt2g + lo * WT2_LD + quad * 8;
    #pragma unroll
    for (int k = 0; k < 4; ++k) {
        bf16x8 af0 = *(const bf16x8*)&h1s[lo][k * 32 + quad * 8];
        bf16x8 af1 = *(const bf16x8*)&h1s[16 + lo][k * 32 + quad * 8];
        #pragma unroll
        for (int nt = 0; nt < 4; ++nt) {
            bf16x8 bB = *(const bf16x8*)(w2row + nt * 16 * WT2_LD + k * 32);
            acc2[0][nt] = __builtin_amdgcn_mfma_f32_16x16x32_bf16(af0, bB, acc2[0][nt], 0, 0, 0);
            acc2[1][nt] = __builtin_amdgcn_mfma_f32_16x16x32_bf16(af1, bB, acc2[1][nt], 0, 0, 0);
        }
    }

    // ---- fast tanh -> hw sincos -> interleaved csn (aliases h1s; same-wave
    //      DS ordering guarantees all h1s reads above complete first) ----
    #pragma unroll
    for (int nt = 0; nt < 4; ++nt) {
        const int col = nt * 16 + lo;
        const float bb = b2[col];
        #pragma unroll
        for (int mt = 0; mt < 2; ++mt) {
            #pragma unroll
            for (int r = 0; r < 4; ++r) {
                float a = fast_tanh(acc2[mt][nt][r] + bb);
                union { unsigned int u; __hip_bfloat16 h[2]; } p;
                p.h[0] = __float2bfloat16(__cosf(a));
                p.h[1] = __float2bfloat16(__sinf(a));
                *(unsigned int*)&csn[mt * 16 + quad * 4 + r][2 * col] = p.u;
            }
        }
    }

    // ---- coalesced global write of interleaved cos/sin (8B per lane) ----
    #pragma unroll
    for (int m = 0; m < 16; ++m) {
        int idx = l + m * 64;             // 0..1023 : 32 rows x 32 qwords
        int row = idx >> 5;
        int q = idx & 31;
        uint2 v = *(const uint2*)&csn[row][q * 4];
        *(uint2*)(csng + (size_t)(n0 + row) * 128 + q * 4) = v;
    }

    // ---- Phase D: per-graph stats; lane = bundle l, channels 4l..4l+3 ----
    const int c0 = 4 * l;
    float xc0 = 0.f, xc1 = 0.f, xc2 = 0.f, xc3 = 0.f;
    float xs0 = 0.f, xs1 = 0.f, xs2 = 0.f, xs3 = 0.f;
    float xm0 = 0.f, xm1 = 0.f, xm2 = 0.f, xm3 = 0.f;
    float xq0 = 0.f, xq1 = 0.f, xq2 = 0.f, xq3 = 0.f;
    float stc = 0.f, sts = 0.f, stcc = 0.f, stcs = 0.f, rcnt = 0.f;
    int gprev = -1;

#define FLUSH_G(gidx) do {                                            \
        float* rec = gsums + (size_t)(gidx) * GREC;                   \
        atomicAdd(&rec[c0 + 0], xc0); atomicAdd(&rec[c0 + 1], xc1);   \
        atomicAdd(&rec[c0 + 2], xc2); atomicAdd(&rec[c0 + 3], xc3);   \
        atomicAdd(&rec[256 + c0 + 0], xs0); atomicAdd(&rec[256 + c0 + 1], xs1); \
        atomicAdd(&rec[256 + c0 + 2], xs2); atomicAdd(&rec[256 + c0 + 3], xs3); \
        atomicAdd(&rec[512 + c0 + 0], stc); atomicAdd(&rec[512 + c0 + 1], sts); \
        atomicAdd(&rec[512 + c0 + 2], stcc); atomicAdd(&rec[512 + c0 + 3], stcs); \
        if (l == 0) atomicAdd(&rec[768], rcnt);                       \
    } while (0)

    #pragma unroll 8
    for (int r = 0; r < BLKN; ++r) {
        const int g = gsh[r];
        if (g != gprev) {                 // wave-uniform branch
            if (gprev >= 0) FLUSH_G(gprev);
            xc0 = xc1 = xc2 = xc3 = 0.f;
            xs0 = xs1 = xs2 = xs3 = 0.f;
            stc = sts = stcc = stcs = 0.f;
            rcnt = 0.f;
            gprev = g;
        }
        const float4 xv = *(const float4*)(x + (size_t)(n0 + r) * C + c0);
        union { unsigned int u; __hip_bfloat16 h[2]; } cs;
        cs.u = *(const unsigned int*)&csn[r][2 * l];
        const float cv = bf2f(cs.h[0]);
        const float sv = bf2f(cs.h[1]);
        xc0 += xv.x * cv; xc1 += xv.y * cv; xc2 += xv.z * cv; xc3 += xv.w * cv;
        xs0 += xv.x * sv; xs1 += xv.y * sv; xs2 += xv.z * sv; xs3 += xv.w * sv;
        xm0 += xv.x; xm1 += xv.y; xm2 += xv.z; xm3 += xv.w;
        xq0 += xv.x * xv.x; xq1 += xv.y * xv.y; xq2 += xv.z * xv.z; xq3 += xv.w * xv.w;
        stc += cv; sts += sv; stcc += cv * cv; stcs += cv * sv;
        rcnt += 1.f;
    }
    if (gprev >= 0) FLUSH_G(gprev);
#undef FLUSH_G

    // BN partials: non-atomic, coalesced float4; reduced in K2's prologue
    float4 m4; m4.x = xm0; m4.y = xm1; m4.z = xm2; m4.w = xm3;
    float4 q4; q4.x = xq0; q4.y = xq1; q4.z = xq2; q4.w = xq3;
    *(float4*)&pbn[(size_t)wid * 512 + c0] = m4;
    *(float4*)&pbn[(size_t)wid * 512 + 256 + c0] = q4;
}

// ---------------------------------------------------------------------------
// K2: prologue: block g reduces a contiguous r-chunk of pbn over ALL channels
//     (coalesced wave reads), one atomicAdd per channel per block.
//     Then per graph: reconstruct rotated pool sums, hmean = (grot@lin_w)/cnt+b;
//     add closed-form BN contributions of o = x + R^T hmean to bnsum/bnsq.
// ---------------------------------------------------------------------------
__global__ __launch_bounds__(256)
void k2_hmean_stats(const float* __restrict__ gsums,
                    const float* __restrict__ pbn,
                    const float* __restrict__ lin_w, const float* __restrict__ lin_b,
                    float* __restrict__ hmean,
                    float* __restrict__ bnsum, float* __restrict__ bnsq)
{
    __shared__ float xc[C], xsv[C], bs4[C], grot[C], hm[C];
    __shared__ float cnt_sh;
    const int g = blockIdx.x;
    const int t = threadIdx.x;

    {
        const int chunk = (NPART + NG - 1) / NG;   // 25
        const int r0 = g * chunk;
        const int r1 = (r0 + chunk < NPART) ? (r0 + chunk) : NPART;
        if (r0 < r1) {
            float a0 = 0.f, a1 = 0.f;
            for (int r = r0; r < r1; ++r) {
                a0 += pbn[(size_t)r * 512 + t];
                a1 += pbn[(size_t)r * 512 + 256 + t];
            }
            atomicAdd(&bnsum[t], a0);
            atomicAdd(&bnsq[t], a1);
        }
    }

    const float* rec = gsums + (size_t)g * GREC;
    xc[t]  = rec[t];
    xsv[t] = rec[256 + t];
    bs4[t] = rec[512 + t];
    if (t == 0) cnt_sh = rec[768];
    __syncthreads();

    const int b = t >> 2, idx2 = t & 3, i2 = idx2 >> 1;
    // rotated pool sum: c0=4b+f pairs with c1=4b+2+f
    grot[t] = (i2 == 0) ? (xc[t] - xsv[t + 2]) : (xsv[t - 2] + xc[t]);
    __syncthreads();

    float a0 = 0.f, a1 = 0.f, a2 = 0.f, a3 = 0.f;
    #pragma unroll 4
    for (int k = 0; k < C; k += 4) {
        a0 += grot[k + 0] * lin_w[(size_t)(k + 0) * C + t];
        a1 += grot[k + 1] * lin_w[(size_t)(k + 1) * C + t];
        a2 += grot[k + 2] * lin_w[(size_t)(k + 2) * C + t];
        a3 += grot[k + 3] * lin_w[(size_t)(k + 3) * C + t];
    }
    const float cnt = cnt_sh;
    const float hv = (cnt > 0.f) ? ((a0 + a1 + a2 + a3) / cnt + lin_b[t]) : 0.f;
    hm[t] = hv;
    hmean[g * C + t] = hv;
    __syncthreads();

    if (cnt > 0.f) {
        const int f = idx2 & 1;
        const float h0 = hm[4 * b + f];
        const float h1 = hm[4 * b + 2 + f];
        const float CV = bs4[4 * b + 0], SV = bs4[4 * b + 1];
        const float CC = bs4[4 * b + 2], CS = bs4[4 * b + 3];
        const float SS = cnt - CC;       // cv^2+sv^2 = 1 (bf16 eps negligible)
        float sumc, sqc;
        if (i2 == 0) {
            sumc = h0 * CV + h1 * SV;
            sqc  = 2.f * (h0 * xc[t] + h1 * xsv[t])
                 + h0 * h0 * CC + 2.f * h0 * h1 * CS + h1 * h1 * SS;
        } else {
            sumc = -h0 * SV + h1 * CV;
            sqc  = 2.f * (-h0 * xsv[t] + h1 * xc[t])
                 + h0 * h0 * SS - 2.f * h0 * h1 * CS + h1 * h1 * CC;
        }
        atomicAdd(&bnsum[t], sumc);
        atomicAdd(&bnsq[t], sqc);
    }
}

// ---------------------------------------------------------------------------
// K4: o = x + R^T hmean[batch[n]], normalized, single output pass.
// ---------------------------------------------------------------------------
__global__ __launch_bounds__(256, 4)
void k4_fused(const float* __restrict__ x,
              const int* __restrict__ batch,
              const __hip_bfloat16* __restrict__ csng,
              const float* __restrict__ hmean,
              const float* __restrict__ bnsum, const float* __restrict__ bnsq,
              const float* __restrict__ gamma, const float* __restrict__ beta,
              float* __restrict__ out)
{
    __shared__ float mul_s[C], add_s[C];
    const int t = threadIdx.x;
    {
        const float inv_n = 1.0f / (float)N_NODES;
        const float mu = bnsum[t] * inv_n;
        const float var = bnsq[t] * inv_n - mu * mu;
        const float inv = rsqrtf(var + BN_EPS);
        const float m = gamma[t] * inv;
        mul_s[t] = m;
        add_s[t] = beta[t] - mu * m;
    }
    __syncthreads();
    const int s = t >> 6;
    const int cg4 = t & 63;
    const float4 mm = *(const float4*)&mul_s[cg4 * 4];
    const float4 aa = *(const float4*)&add_s[cg4 * 4];

    for (int base = blockIdx.x * 4; base < N_NODES; base += gridDim.x * 4) {
        const int n = base + s;
        if (n < N_NODES) {
            const int g = batch[n];
            const float4 hm = *(const float4*)(hmean + (size_t)g * C + cg4 * 4);
            union { unsigned int u; __hip_bfloat16 h[2]; } cs;
            cs.u = *(const unsigned int*)(csng + (size_t)n * 128 + cg4 * 2);
            const float cv = bf2f(cs.h[0]);
            const float sv = bf2f(cs.h[1]);
            const float4 xv = *(const float4*)(x + (size_t)n * C + cg4 * 4);
            float4 o;
            o.x = (xv.x + cv * hm.x + sv * hm.z) * mm.x + aa.x;
            o.y = (xv.y + cv * hm.y + sv * hm.w) * mm.y + aa.y;
            o.z = (xv.z - sv * hm.x + cv * hm.z) * mm.z + aa.z;
            o.w = (xv.w - sv * hm.y + cv * hm.w) * mm.w + aa.w;
            *(float4*)(out + (size_t)n * C + cg4 * 4) = o;
        }
    }
}

// ---------------------------------------------------------------------------
extern "C" void kernel_launch(void* const* d_in, const int* in_sizes, int n_in,
                              void* d_out, int out_size, void* d_ws, size_t ws_size,
                              hipStream_t stream)
{
    const float* x      = (const float*)d_in[0];
    // d_in[1] = edge_index (unused, num_gnn == 0)
    const int* batch    = (const int*)d_in[2];
    const float* W1     = (const float*)d_in[3];
    const float* b1     = (const float*)d_in[4];
    const float* W2     = (const float*)d_in[5];
    const float* b2     = (const float*)d_in[6];
    const float* lin_w  = (const float*)d_in[7];
    const float* lin_b  = (const float*)d_in[8];
    const float* gamma  = (const float*)d_in[9];
    const float* beta   = (const float*)d_in[10];

    float* ws    = (float*)d_ws;
    float* gsums = ws + OFF_GSUMS;
    float* bnsum = ws + OFF_BNSUM;
    float* bnsq  = ws + OFF_BNSQ;
    float* hmean = ws + OFF_HMEAN;
    __hip_bfloat16* Wt1  = (__hip_bfloat16*)(ws + OFF_WT1);
    __hip_bfloat16* Wt2  = (__hip_bfloat16*)(ws + OFF_WT2);
    __hip_bfloat16* csng = (__hip_bfloat16*)(ws + OFF_CSN);
    float* pbn   = ws + OFF_PBN;
    float* out   = (float*)d_out;

    k0_prep<<<512, 256, 0, stream>>>(W1, W2, ws, Wt1, Wt2);
    k1_wave<<<NBLK1, 256, 0, stream>>>(x, batch, Wt1, b1, Wt2, b2,
                                       gsums, pbn, csng);
    k2_hmean_stats<<<NG, 256, 0, stream>>>(gsums, pbn, lin_w, lin_b, hmean, bnsum, bnsq);
    k4_fused<<<2048, 256, 0, stream>>>(x, batch, csng, hmean, bnsum, bnsq,
                                       gamma, beta, out);
}